// Round 1
// baseline (66.515 us; speedup 1.0000x reference)
//
#include <hip/hip_runtime.h>

#define TPL_SIZE 16384
#define TPL_K 16
#define TPL_ND 5

__global__ __launch_bounds__(256) void tp_layer_kernel(
    const float* __restrict__ x,
    const float* __restrict__ points,
    const int*   __restrict__ edge_index,
    const float* __restrict__ dtp,
    const float* __restrict__ dist,
    const float* __restrict__ weight,
    float* __restrict__ out,
    int total)
{
    int gid = blockIdx.x * blockDim.x + threadIdx.x;
    if (gid >= total) return;

    int b = gid >> 14;            // / TPL_SIZE
    int s = gid & (TPL_SIZE - 1); // % TPL_SIZE

    const float* pb = points + (size_t)b * TPL_SIZE * 2;
    const float* xb = x + (size_t)b * TPL_SIZE;

    float2 p = *reinterpret_cast<const float2*>(pb + 2 * s);
    float  v = xb[s];

    const int4*   ei = reinterpret_cast<const int4*>(edge_index + ((size_t)b * TPL_SIZE + s) * TPL_K);
    const float4* dw = reinterpret_cast<const float4*>(dist      + ((size_t)b * TPL_SIZE + s) * TPL_K);

    // 15 unique entries of symmetric AtA (upper triangle, row-major) + Atb
    float ata[15];
    float atb[TPL_ND];
    #pragma unroll
    for (int i = 0; i < 15; ++i) ata[i] = 0.0f;
    #pragma unroll
    for (int i = 0; i < TPL_ND; ++i) atb[i] = 0.0f;

    #pragma unroll
    for (int q = 0; q < 4; ++q) {
        int4   iv = ei[q];
        float4 wv = dw[q];
        int   idxs[4] = {iv.x, iv.y, iv.z, iv.w};
        float ws[4]   = {wv.x, wv.y, wv.z, wv.w};
        #pragma unroll
        for (int t = 0; t < 4; ++t) {
            int   id = idxs[t];
            float w  = ws[t];
            float2 np = *reinterpret_cast<const float2*>(pb + 2 * id);
            float  nv = xb[id];
            float dx = np.x - p.x;
            float dy = np.y - p.y;
            // Taylor monomials: dx, dy, dx^2/2, dx*dy, dy^2/2 (EXPS order), weighted
            float a[TPL_ND];
            a[0] = dx * w;
            a[1] = dy * w;
            a[2] = 0.5f * dx * dx * w;
            a[3] = dx * dy * w;
            a[4] = 0.5f * dy * dy * w;
            float bwv = (nv - v) * w;
            int c = 0;
            #pragma unroll
            for (int i = 0; i < TPL_ND; ++i) {
                #pragma unroll
                for (int j = i; j < TPL_ND; ++j) {
                    ata[c++] += a[i] * a[j];
                }
                atb[i] += a[i] * bwv;
            }
        }
    }

    // Expand to full 5x5 + ridge, solve via unrolled Gaussian elimination
    // (AtA + 1e-6 I is SPD -> no pivoting needed; all indices compile-time
    //  after unroll -> stays in registers)
    float M[TPL_ND][TPL_ND];
    float r[TPL_ND];
    {
        int c = 0;
        #pragma unroll
        for (int i = 0; i < TPL_ND; ++i) {
            #pragma unroll
            for (int j = i; j < TPL_ND; ++j) {
                M[i][j] = ata[c];
                M[j][i] = ata[c];
                ++c;
            }
            r[i] = atb[i];
            M[i][i] += 1e-6f;
        }
    }

    #pragma unroll
    for (int i = 0; i < TPL_ND; ++i) {
        float inv = 1.0f / M[i][i];
        #pragma unroll
        for (int j = i + 1; j < TPL_ND; ++j) {
            float f = M[j][i] * inv;
            #pragma unroll
            for (int cc = i + 1; cc < TPL_ND; ++cc) {
                M[j][cc] -= f * M[i][cc];
            }
            r[j] -= f * r[i];
        }
    }

    float sol[TPL_ND];
    #pragma unroll
    for (int i = TPL_ND - 1; i >= 0; --i) {
        float sv = r[i];
        #pragma unroll
        for (int cc = i + 1; cc < TPL_ND; ++cc) sv -= M[i][cc] * sol[cc];
        sol[i] = sv / M[i][i];
    }

    float du = 0.0f;
    #pragma unroll
    for (int i = 0; i < TPL_ND; ++i) du += sol[i] * weight[i];

    out[gid] = v + dtp[0] * du;
}

extern "C" void kernel_launch(void* const* d_in, const int* in_sizes, int n_in,
                              void* d_out, int out_size, void* d_ws, size_t ws_size,
                              hipStream_t stream) {
    const float* x          = (const float*)d_in[0];
    const float* points     = (const float*)d_in[1];
    const int*   edge_index = (const int*)d_in[2];
    const float* dtp        = (const float*)d_in[3];
    const float* dist       = (const float*)d_in[4];
    const float* weight     = (const float*)d_in[5];
    float* out = (float*)d_out;

    int total = out_size;  // B * SIZE = 32 * 16384 = 524288
    int block = 256;
    int grid  = (total + block - 1) / block;
    tp_layer_kernel<<<grid, block, 0, stream>>>(x, points, edge_index, dtp,
                                                dist, weight, out, total);
}